// Round 7
// baseline (371.290 us; speedup 1.0000x reference)
//
#include <hip/hip_runtime.h>
#include <math.h>

// Problem constants (from reference setup_inputs): B=16, A=16384, C=81, TOP_K=64
constexpr int B_N  = 16;
constexpr int A_N  = 16384;
constexpr int C_N  = 81;
constexpr int TOPK = 64;
constexpr int DNT  = 256;            // decode kernel block size
constexpr int NBINS = 232;           // score-bit bins covering (0.3, 1.0)
constexpr int CAP   = 512;           // per-band capacity (pow2, 8/lane)
constexpr unsigned BIN_BASE = 0x3E99u;   // __float_as_uint(0.3f) >> 16
constexpr int SNT = 256;             // streaming select block size
constexpr int BC_N = B_N * C_N;      // 1296
constexpr int GCAP_MAX = 16384;      // bucket ALL candidates if ws allows

// Exact-compare constant: fl32(inter/den) > 0.5  <=>  inter > den*(0.5+2^-25)
// (24x25-bit mantissa product exact in f64; RN monotone.) Proven r5/r6.
#define IOU_HALF_EXACT 0x1.000001p-1

// sigmoid+transpose tile: 64 anchors x 81 classes, linear LDS (round-1 v4).
constexpr int TA   = 64;
constexpr int TNT  = 256;
constexpr int TILE_ELEMS = TA * C_N;       // 5184
constexpr int TILE_F4    = TILE_ELEMS / 4; // 1296

// ---------------------------------------------------------------------------
// Kernel 1: SSD box decode (unchanged — bit-exact vs ref across all rounds).
// ---------------------------------------------------------------------------
__global__ __launch_bounds__(DNT) void decode_kernel(const float4* __restrict__ loc,
                                                     const float4* __restrict__ anch,
                                                     float4* __restrict__ boxes) {
    int i = blockIdx.x * DNT + threadIdx.x;
    int a = i & (A_N - 1);
    float4 l  = loc[i];
    float4 an = anch[a];
    float cx = an.x + (l.x * 0.1f) * an.z;
    float cy = an.y + (l.y * 0.1f) * an.w;
    float w  = an.z * expf(l.z * 0.2f);
    float h  = an.w * expf(l.w * 0.2f);
    float x1 = cx - w * 0.5f;
    float y1 = cy - h * 0.5f;
    boxes[i] = make_float4(x1, y1, x1 + w, y1 + h);
}

// ---------------------------------------------------------------------------
// Kernel 1b: fused sigmoid + transpose (round-1 v4, passed).
// ---------------------------------------------------------------------------
__global__ __launch_bounds__(TNT) void sigT_kernel(const float* __restrict__ conf,
                                                   float* __restrict__ scoresT) {
    __shared__ float4 tile4[TILE_F4];          // 20.7 KB, linear (mirrors global)
    float* tile = (float*)tile4;

    const int a0 = blockIdx.x * TA;
    const int b  = blockIdx.y;
    const int t  = threadIdx.x;

    const float4* src = (const float4*)(conf + ((size_t)b * A_N + a0) * C_N);
#pragma unroll
    for (int i = 0; i < (TILE_F4 + TNT - 1) / TNT; ++i) {   // 6 iters (last partial)
        int idx4 = i * TNT + t;
        if (idx4 < TILE_F4) {
            float4 x = src[idx4];                            // dwordx4, coalesced
            float4 v;
            v.x = 1.0f / (1.0f + expf(-x.x));
            v.y = 1.0f / (1.0f + expf(-x.y));
            v.z = 1.0f / (1.0f + expf(-x.z));
            v.w = 1.0f / (1.0f + expf(-x.w));
            tile4[idx4] = v;                                 // ds_write_b128, dense
        }
    }
    __syncthreads();
    float* dst = scoresT + (size_t)b * C_N * A_N + a0;
#pragma unroll
    for (int i = 0; i < (TILE_F4 + TNT - 1) / TNT; ++i) {
        int idx4 = i * TNT + t;
        if (idx4 < TILE_F4) {
            int cc  = idx4 >> 4;                   // 16 float4 per class row
            int al4 = idx4 & 15;
            int e   = al4 * 4 * C_N + cc;
            float4 v;
            v.x = tile[e];
            v.y = tile[e + C_N];
            v.z = tile[e + 2 * C_N];
            v.w = tile[e + 3 * C_N];
            ((float4*)(dst + (size_t)cc * A_N))[al4] = v;   // dwordx4 stores
        }
    }
}

// ---------------------------------------------------------------------------
// Exact IoU>0.5 test (accepted box A first — matches ref operand order).
// ---------------------------------------------------------------------------
__device__ __forceinline__ bool iou_gt_half(const float4& A, float aA,
                                            const float4& Bx, float aB) {
    float tlx = fmaxf(A.x, Bx.x);
    float tly = fmaxf(A.y, Bx.y);
    float brx = fminf(A.z, Bx.z);
    float bry = fminf(A.w, Bx.w);
    float iw  = fmaxf(brx - tlx, 0.0f);
    float ih  = fmaxf(bry - tly, 0.0f);
    float inter = iw * ih;
    float den = aA + aB - inter;                 // fl(fl(aA+aB)-inter), ref order
    return (double)inter > (double)den * IOU_HALF_EXACT;
}

// ---------------------------------------------------------------------------
// 8-reg suppress (r6 verbatim semantics via iou_gt_half).
// ---------------------------------------------------------------------------
__device__ __forceinline__ void suppress_mask(
        unsigned& aliveM, const float4& bb, float bar,
        const float4 (&breg)[8], const float (&careg)[8]) {
#pragma unroll
    for (int r = 0; r < 8; ++r)
        if (iou_gt_half(bb, bar, breg[r], careg[r])) aliveM &= ~(1u << r);
}

// ---------------------------------------------------------------------------
// OLD scan routine (kept verbatim for tier-2/tier-3 fallback paths).
// ---------------------------------------------------------------------------
__device__ __forceinline__ void sort_gather_scan64(
        unsigned long long* cand, float4* cbox, int C, int lane,
        const float4* __restrict__ bptr, float* __restrict__ optr,
        float& rx1, float& ry1, float& rx2, float& ry2, float& rar,
        int& acc, int& kout) {
    unsigned long long key[8];
#pragma unroll
    for (int r = 0; r < 8; ++r) {
        int sidx = r * 64 + lane;
        key[r] = (sidx < C) ? cand[sidx] : 0ull;   // pad: 0 < any real key
    }
#pragma unroll
    for (int k = 2; k <= CAP; k <<= 1) {
#pragma unroll
        for (int j = k >> 1; j > 0; j >>= 1) {
            if (j >= 64) {
                int jr = j >> 6;
#pragma unroll
                for (int r = 0; r < 8; ++r) {
                    int rp = r ^ jr;
                    if (rp > r) {
                        int e = r * 64 + lane;
                        bool up = ((e & k) == 0);
                        unsigned long long va = key[r], vb = key[rp];
                        bool sw = up ? (va < vb) : (va > vb);
                        if (sw) { key[r] = vb; key[rp] = va; }
                    }
                }
            } else {
#pragma unroll
                for (int r = 0; r < 8; ++r) {
                    int e = r * 64 + lane;
                    bool up    = ((e & k) == 0);
                    bool isLow = ((lane & j) == 0);
                    unsigned long long va = key[r];
                    unsigned long long vb = __shfl_xor(va, j, 64);
                    bool keepMax = (up == isLow);
                    key[r] = keepMax ? (va > vb ? va : vb) : (va < vb ? va : vb);
                }
            }
        }
    }
    __syncthreads();
#pragma unroll
    for (int r = 0; r < 8; ++r) cand[r * 64 + lane] = key[r];
    __syncthreads();
#pragma unroll
    for (int r = 0; r < 8; ++r) {
        int e = r * 64 + lane;
        if (e < C) cbox[e] = bptr[(int)(~(unsigned)cand[e])];
    }
    __syncthreads();

    int ts = 0;
    unsigned long long k0 = cand[0];
    float4 cb = cbox[0];
    while (ts < C) {
        unsigned long long nk = 0ull;
        float4 nb = cb;
        if (ts + 1 < C) { nk = cand[ts + 1]; nb = cbox[ts + 1]; }
        float sc = __uint_as_float((unsigned)(k0 >> 32));
        float ca = (cb.z - cb.x) * (cb.w - cb.y);
        bool over = false;
        if (lane < acc) {
            float tlx = fmaxf(rx1, cb.x);
            float tly = fmaxf(ry1, cb.y);
            float brx = fminf(rx2, cb.z);
            float bry = fminf(ry2, cb.w);
            float iw  = fmaxf(brx - tlx, 0.0f);
            float ih  = fmaxf(bry - tly, 0.0f);
            float inter = iw * ih;
            float iou = inter / (rar + ca - inter);
            over = iou > 0.5f;
        }
        if (!__any(over)) {
            if (lane == acc) { rx1 = cb.x; ry1 = cb.y; rx2 = cb.z; ry2 = cb.w; rar = ca; }
            if (lane == 0) {
                float* o = optr + (size_t)kout * 5;
                o[0] = sc; o[1] = cb.x; o[2] = cb.y; o[3] = cb.z; o[4] = cb.w;
            }
            acc++; kout++;
            if (acc == TOPK) break;
        }
        ++ts; k0 = nk; cb = nb;
    }
}

// ---------------------------------------------------------------------------
// Full-band processor (r5/r6-proven): 512 bitonic sort + gather + pre-suppress
// + ballot accept. Used for band 0 (acc==0) and rare large survivor sets.
// ---------------------------------------------------------------------------
__device__ __forceinline__ void sort_mask_accept(
        unsigned long long (&key)[8], int C, int lane,
        unsigned long long* cand, float4* cbox, float4* abox, float* aar,
        const float4* __restrict__ bptr, float* __restrict__ optr,
        int& acc, int& kout) {
#pragma unroll
    for (int k = 2; k <= CAP; k <<= 1) {
#pragma unroll
        for (int j = k >> 1; j > 0; j >>= 1) {
            if (j >= 64) {
                int jr = j >> 6;
#pragma unroll
                for (int r = 0; r < 8; ++r) {
                    int rp = r ^ jr;
                    if (rp > r) {
                        int e = r * 64 + lane;
                        bool up = ((e & k) == 0);
                        unsigned long long va = key[r], vb = key[rp];
                        bool sw = up ? (va < vb) : (va > vb);
                        if (sw) { key[r] = vb; key[rp] = va; }
                    }
                }
            } else {
#pragma unroll
                for (int r = 0; r < 8; ++r) {
                    int e = r * 64 + lane;
                    bool up    = ((e & k) == 0);
                    bool isLow = ((lane & j) == 0);
                    unsigned long long va = key[r];
                    unsigned long long vb = __shfl_xor(va, j, 64);
                    bool keepMax = (up == isLow);
                    key[r] = keepMax ? (va > vb ? va : vb) : (va < vb ? va : vb);
                }
            }
        }
    }
    __syncthreads();
#pragma unroll
    for (int r = 0; r < 8; ++r) cand[r * 64 + lane] = key[r];   // for broadcasts
    __syncthreads();

    float4 breg[8];
    float  careg[8];
#pragma unroll
    for (int r = 0; r < 8; ++r) {
        int e = r * 64 + lane;
        float4 v = make_float4(0.f, 0.f, 0.f, 0.f);
        if (e < C) { v = bptr[(int)(~(unsigned)key[r])]; cbox[e] = v; }
        breg[r]  = v;
        careg[r] = (v.z - v.x) * (v.w - v.y);
    }
    __syncthreads();

    unsigned aliveM = 0;
#pragma unroll
    for (int r = 0; r < 8; ++r)
        if (r * 64 + lane < C) aliveM |= (1u << r);

    for (int a = 0; a < acc; ++a) {
        suppress_mask(aliveM, abox[a], aar[a], breg, careg);
        if (!__any(aliveM != 0u)) break;
    }

    int rStart = 0;
    while (acc < TOPK) {
        int estar = -1;
        for (int r = rStart; r < 8; ++r) {
            unsigned long long m = __ballot((aliveM >> r) & 1);
            if (m != 0ull) { estar = r * 64 + __builtin_ctzll(m); rStart = r; break; }
        }
        if (estar < 0) break;

        unsigned long long k0 = cand[estar];
        float4 bb = cbox[estar];
        float sc  = __uint_as_float((unsigned)(k0 >> 32));
        float bar = (bb.z - bb.x) * (bb.w - bb.y);

        if (lane == 0) {
            float* o = optr + (size_t)kout * 5;
            o[0] = sc; o[1] = bb.x; o[2] = bb.y; o[3] = bb.z; o[4] = bb.w;
            abox[acc] = bb; aar[acc] = bar;
        }
        acc++; kout++;

        suppress_mask(aliveM, bb, bar, breg, careg);
    }
}

// ---------------------------------------------------------------------------
// Small accept path (<=64 survivors): RANK SORT via LDS broadcast reads
// (replaces 21-stage 64-bit shfl bitonic — r4 showed shfl chains are poison).
// Keys unique -> ranks bijective -> exact sorted order. Then ballot accepts
// with 1 IoU/lane (r6 small-path semantics verbatim).
// ---------------------------------------------------------------------------
__device__ __forceinline__ void small_accept(
        int C1, int lane,
        unsigned long long* candS, float4* cboxS,        // survivors [0..C1)
        unsigned long long* sortK, float4* sortB,        // scratch [0..64)
        float4* abox, float* aar,
        float* __restrict__ optr, int& acc, int& kout) {
    unsigned long long myk = (lane < C1) ? candS[lane] : 0ull;
    float4 myb = (lane < C1) ? cboxS[lane] : make_float4(0.f, 0.f, 0.f, 0.f);
    int rank = 0;
    for (int m = 0; m < C1; ++m)                         // LDS broadcast reads
        rank += (candS[m] > myk) ? 1 : 0;
    if (lane < C1) { sortK[rank] = myk; sortB[rank] = myb; }
    __syncthreads();

    unsigned long long k2 = (lane < C1) ? sortK[lane] : 0ull;
    float4 b2 = (lane < C1) ? sortB[lane] : make_float4(0.f, 0.f, 0.f, 0.f);
    float a2 = (b2.z - b2.x) * (b2.w - b2.y);
    bool alive = (lane < C1);
    (void)k2;

    while (acc < TOPK) {
        unsigned long long m = __ballot(alive);
        if (m == 0ull) break;
        int e = __builtin_ctzll(m);
        unsigned long long kk = sortK[e];                // broadcast
        float4 wb = sortB[e];                            // broadcast
        float war = (wb.z - wb.x) * (wb.w - wb.y);
        if (lane == 0) {
            float* o = optr + (size_t)kout * 5;
            o[0] = __uint_as_float((unsigned)(kk >> 32));
            o[1] = wb.x; o[2] = wb.y; o[3] = wb.z; o[4] = wb.w;
            abox[acc] = wb; aar[acc] = war;
        }
        acc++; kout++;
        if (alive && iou_gt_half(wb, war, b2, a2)) alive = false;  // self: IoU=1
    }
}

// ---------------------------------------------------------------------------
// Kernel 2a: STREAMING SELECT (r5/r6 counting-sort version, verbatim).
// ---------------------------------------------------------------------------
__global__ __launch_bounds__(SNT) void select_kernel(
        const float* __restrict__ scoresT,
        unsigned long long* __restrict__ g_cand,
        int* __restrict__ g_hist,
        int gcap) {
    __shared__ int hist[NBINS];
    __shared__ int cur[NBINS];
    __shared__ int sfx[NBINS + 1];

    const int bc = blockIdx.x;
    const int t  = threadIdx.x;

    for (int i = t; i < NBINS; i += SNT) { hist[i] = 0; cur[i] = 0; }
    __syncthreads();

    const float4* sptr = (const float4*)(scoresT + (size_t)bc * A_N);

    for (int i = 0; i < A_N / 4 / SNT; ++i) {
        float4 s4 = sptr[t + SNT * i];
        float s[4] = {s4.x, s4.y, s4.z, s4.w};
#pragma unroll
        for (int q = 0; q < 4; ++q) {
            if (s[q] > 0.3f) {
                unsigned u = __float_as_uint(s[q]);
                int bin = (int)(u >> 16) - (int)BIN_BASE;
                bin = bin < 0 ? 0 : (bin > NBINS - 1 ? NBINS - 1 : bin);
                atomicAdd(&hist[bin], 1);
            }
        }
    }
    __syncthreads();

    for (int i = t; i < NBINS; i += SNT) g_hist[bc * NBINS + i] = hist[i];
    if (t == 0) {
        sfx[NBINS] = 0;
        for (int b = NBINS - 1; b >= 0; --b) sfx[b] = sfx[b + 1] + hist[b];
    }
    __syncthreads();

    unsigned long long* gc = g_cand + (size_t)bc * gcap;
    for (int i = 0; i < A_N / 4 / SNT; ++i) {
        float4 s4 = sptr[t + SNT * i];
        float s[4] = {s4.x, s4.y, s4.z, s4.w};
#pragma unroll
        for (int q = 0; q < 4; ++q) {
            if (s[q] > 0.3f) {
                unsigned u = __float_as_uint(s[q]);
                int bin = (int)(u >> 16) - (int)BIN_BASE;
                bin = bin < 0 ? 0 : (bin > NBINS - 1 ? NBINS - 1 : bin);
                int base = sfx[bin + 1];
                if (base < gcap) {
                    int g = base + atomicAdd(&cur[bin], 1);
                    if (g < gcap) {
                        unsigned a = (unsigned)(4 * (t + SNT * i) + q);
                        gc[g] = ((unsigned long long)u << 32) | (unsigned)(~a);
                    }
                }
            }
        }
    }
}

// ---------------------------------------------------------------------------
// Kernel 2b: BANDED NMS v7. Per band (acc>0): gather -> TIERED pre-suppress
// (8-reg chunks of 8 accepted; after 16, compact; if <=64 survivors continue
// at 1 reg/lane) -> rank-sort small path. Chunked suppression is an
// order-independent AND => selection identical to r6 (passed).
// ---------------------------------------------------------------------------
__global__ __launch_bounds__(64, 2) void nms_banded_kernel(
        const float* __restrict__ scoresT,
        const float4* __restrict__ boxes,
        const unsigned long long* __restrict__ g_cand,
        const int* __restrict__ g_hist,
        float* __restrict__ out,
        int gcap) {
    __shared__ int sfx[257];
    __shared__ unsigned long long cand[CAP];
    __shared__ float4 cbox[CAP];
    __shared__ float4 abox[TOPK];
    __shared__ float  aar[TOPK];
    __shared__ int s_cnt;

    const int bc   = blockIdx.x;
    const int b    = bc / C_N;
    const int lane = threadIdx.x;

    const float4* sptr = (const float4*)(scoresT + (size_t)bc * A_N);
    const float4* bptr = boxes + (size_t)b * A_N;
    const unsigned long long* gc = g_cand + (size_t)bc * gcap;
    float* optr = out + (size_t)bc * TOPK * 5;

    // ---- hist -> regs -> shfl suffix-scan -> sfx (r6 verbatim) ----
    const int* gh = g_hist + bc * NBINS;
    int4 hv = make_int4(0, 0, 0, 0);
    if (lane < NBINS / 4) hv = ((const int4*)gh)[lane];
    int s = hv.x + hv.y + hv.z + hv.w;
#pragma unroll
    for (int j = 1; j < 64; j <<= 1) {
        int tv = __shfl_down(s, j, 64);
        if (lane + j < 64) s += tv;
    }
    sfx[4 * lane + 0] = s;
    sfx[4 * lane + 1] = s - hv.x;
    sfx[4 * lane + 2] = s - hv.x - hv.y;
    sfx[4 * lane + 3] = s - hv.x - hv.y - hv.z;
    if (lane == 0) sfx[256] = 0;
    __syncthreads();

    int acc = 0, kout = 0;
    int bin_hi = NBINS;

    while (acc < TOPK && bin_hi > 0) {
        const int base = sfx[bin_hi];
        // ---- parallel band walk (r6 verbatim) ----
        int lostar = bin_hi;
        for (int off = 0; off < bin_hi; off += 64) {
            int l = bin_hi - 1 - off - lane;
            bool ok = (l >= 0) && (sfx[l] - base <= CAP);
            unsigned long long m = __ballot(ok);
            if (m == 0ull) break;
            unsigned long long inv = ~m;
            int nok = (inv == 0ull) ? 64 : __builtin_ctzll(inv);
            lostar = bin_hi - off - nok;
            if (nok < 64) break;
        }
        int bin_lo, C;
        if (lostar < bin_hi) { bin_lo = lostar; C = sfx[bin_lo] - base; }
        else { bin_lo = bin_hi - 1; C = sfx[bin_lo] - base; if (C > CAP) C = CAP; }

        if (C > 0) {
            // ---- load band keys (direct slice or unrolled rescan) ----
            unsigned long long key[8];
            int Cb = C;
            if (base + C <= gcap) {
#pragma unroll
                for (int r = 0; r < 8; ++r) {
                    int e = r * 64 + lane;
                    key[r] = (e < Cb) ? gc[base + e] : 0ull;
                }
            } else {
                if (lane == 0) s_cnt = 0;
                __syncthreads();
#pragma unroll 4
                for (int i = 0; i < A_N / 4 / 64; ++i) {
                    float4 s4 = sptr[lane + 64 * i];
                    float sv[4] = {s4.x, s4.y, s4.z, s4.w};
#pragma unroll
                    for (int q = 0; q < 4; ++q) {
                        if (sv[q] > 0.3f) {
                            unsigned u = __float_as_uint(sv[q]);
                            int bin = (int)(u >> 16) - (int)BIN_BASE;
                            bin = bin < 0 ? 0 : (bin > NBINS - 1 ? NBINS - 1 : bin);
                            if (bin >= bin_lo && bin < bin_hi) {
                                int slot = atomicAdd(&s_cnt, 1);
                                if (slot < CAP) {
                                    unsigned a = (unsigned)(4 * (lane + 64 * i) + q);
                                    cand[slot] = ((unsigned long long)u << 32) | (unsigned)(~a);
                                }
                            }
                        }
                    }
                }
                __syncthreads();
                Cb = s_cnt; if (Cb > CAP) Cb = CAP;
#pragma unroll
                for (int r = 0; r < 8; ++r) {
                    int e = r * 64 + lane;
                    key[r] = (e < Cb) ? cand[e] : 0ull;
                }
                __syncthreads();
            }

            if (Cb > 0) {
                if (acc == 0) {
                    sort_mask_accept(key, Cb, lane, cand, cbox, abox, aar,
                                     bptr, optr, acc, kout);
                } else {
                    // ---- gather boxes + areas to regs ----
                    float4 breg[8];
                    float  careg[8];
#pragma unroll
                    for (int r = 0; r < 8; ++r) {
                        int e = r * 64 + lane;
                        float4 v = make_float4(0.f, 0.f, 0.f, 0.f);
                        if (e < Cb) v = bptr[(int)(~(unsigned)key[r])];
                        else        key[r] = 0ull;
                        breg[r]  = v;
                        careg[r] = (v.z - v.x) * (v.w - v.y);
                    }
                    unsigned aliveM = 0;
#pragma unroll
                    for (int r = 0; r < 8; ++r)
                        if (r * 64 + lane < Cb) aliveM |= (1u << r);

                    // ---- tiered pre-suppression ----
                    int aDone = 0;
                    bool narrowed = false;
                    int  C2 = 0;
                    bool anyAlive = true;
                    while (aDone < acc) {
                        int aEnd = aDone + 8; if (aEnd > acc) aEnd = acc;
                        for (int a = aDone; a < aEnd; ++a)
                            suppress_mask(aliveM, abox[a], aar[a], breg, careg);
                        aDone = aEnd;
                        if (!__any(aliveM != 0u)) { anyAlive = false; break; }
                        if (aDone == 16 && aDone < acc) {
                            // one-shot narrow attempt: compact alive -> LDS
                            int cb2 = 0;
#pragma unroll
                            for (int r = 0; r < 8; ++r) {
                                unsigned long long m = __ballot((aliveM >> r) & 1u);
                                int pre = (int)__popcll(m & ((1ull << lane) - 1ull));
                                if ((aliveM >> r) & 1u) {
                                    cand[cb2 + pre] = key[r];
                                    cbox[cb2 + pre] = breg[r];
                                }
                                cb2 += (int)__popcll(m);
                            }
                            C2 = cb2;
                            __syncthreads();
                            if (C2 <= 64) { narrowed = true; break; }
                            // else: continue wide with original regs
                        }
                    }

                    if (anyAlive) {
                        if (narrowed) {
                            // ---- Phase B: 1 reg/lane over compacted set ----
                            unsigned long long k1 =
                                (lane < C2) ? cand[lane] : 0ull;
                            float4 b1 = (lane < C2) ? cbox[lane]
                                                    : make_float4(0.f, 0.f, 0.f, 0.f);
                            float ar1 = (b1.z - b1.x) * (b1.w - b1.y);
                            bool alive1 = (lane < C2);
                            while (aDone < acc) {
                                int aEnd = aDone + 8; if (aEnd > acc) aEnd = acc;
                                for (int a = aDone; a < aEnd; ++a)
                                    if (alive1 && iou_gt_half(abox[a], aar[a], b1, ar1))
                                        alive1 = false;
                                aDone = aEnd;
                                if (!__any(alive1)) break;
                            }
                            unsigned long long m = __ballot(alive1);
                            int C1 = (int)__popcll(m);
                            if (C1 > 0) {
                                int pre = (int)__popcll(m & ((1ull << lane) - 1ull));
                                if (alive1) { cand[pre] = k1; cbox[pre] = b1; }
                                __syncthreads();
                                small_accept(C1, lane, cand, cbox,
                                             cand + 64, cbox + 64,
                                             abox, aar, optr, acc, kout);
                            }
                        } else {
                            // ---- wide end: compact survivors (r6 verbatim) ----
                            int cb2 = 0;
#pragma unroll
                            for (int r = 0; r < 8; ++r) {
                                unsigned long long m = __ballot((aliveM >> r) & 1u);
                                int pre = (int)__popcll(m & ((1ull << lane) - 1ull));
                                if ((aliveM >> r) & 1u) {
                                    cand[cb2 + pre] = key[r];
                                    cbox[cb2 + pre] = breg[r];
                                }
                                cb2 += (int)__popcll(m);
                            }
                            const int C1 = cb2;
                            __syncthreads();
                            if (C1 > 64) {
                                unsigned long long k2[8];
#pragma unroll
                                for (int r = 0; r < 8; ++r) {
                                    int e = r * 64 + lane;
                                    k2[r] = (e < C1) ? cand[e] : 0ull;
                                }
                                __syncthreads();
                                sort_mask_accept(k2, C1, lane, cand, cbox,
                                                 abox, aar, bptr, optr, acc, kout);
                            } else if (C1 > 0) {
                                small_accept(C1, lane, cand, cbox,
                                             cand + 64, cbox + 64,
                                             abox, aar, optr, acc, kout);
                            }
                        }
                    }
                }
            }
        }
        bin_hi = bin_lo;
    }

    // Zero-fill remaining rows (harness poisons d_out with 0xAA every launch).
    {
        float* o  = optr + (size_t)kout * 5;
        int   rem = (TOPK - kout) * 5;
        for (int i = lane; i < rem; i += 64) o[i] = 0.0f;
    }
}

// ---------------------------------------------------------------------------
// Tier-2: round-0 fused select+NMS (proven 80 µs) if ws lacks split buffers.
// ---------------------------------------------------------------------------
__global__ __launch_bounds__(SNT, 4) void select_nms_fused(
        const float* __restrict__ scoresT,
        const float4* __restrict__ boxes,
        float* __restrict__ out) {
    __shared__ int hist[NBINS];
    __shared__ unsigned long long cand[CAP];
    __shared__ float4 cbox[CAP];
    __shared__ int s_cnt, s_acc, s_kout;

    const int bc   = blockIdx.x;
    const int b    = bc / C_N;
    const int t    = threadIdx.x;
    const int lane = t & 63;
    const int wv   = t >> 6;

    for (int i = t; i < NBINS; i += SNT) hist[i] = 0;
    if (t == 0) { s_acc = 0; s_kout = 0; }
    __syncthreads();

    const float4* sptr = (const float4*)(scoresT + (size_t)bc * A_N);
    const float4* bptr = boxes + (size_t)b * A_N;
    float* optr = out + (size_t)bc * TOPK * 5;

    for (int i = 0; i < A_N / 4 / SNT; ++i) {
        float4 s4 = sptr[t + SNT * i];
        float s[4] = {s4.x, s4.y, s4.z, s4.w};
#pragma unroll
        for (int q = 0; q < 4; ++q) {
            if (s[q] > 0.3f) {
                unsigned u = __float_as_uint(s[q]);
                int bin = (int)(u >> 16) - (int)BIN_BASE;
                bin = bin < 0 ? 0 : (bin > NBINS - 1 ? NBINS - 1 : bin);
                atomicAdd(&hist[bin], 1);
            }
        }
    }
    __syncthreads();

    float rx1 = 0.f, ry1 = 0.f, rx2 = 0.f, ry2 = 0.f, rar = 0.f;
    int acc = 0, kout = 0;

    int bin_hi = NBINS;
    for (;;) {
        int lo = bin_hi, tot = 0;
        while (lo > 0) {
            int cnt = hist[lo - 1];
            if (tot + cnt > CAP) { if (tot == 0) { lo--; } break; }
            tot += cnt; lo--;
        }
        const int bin_lo = lo;
        if (bin_lo == bin_hi) break;
        if (t == 0) s_cnt = 0;
        __syncthreads();

        for (int i = 0; i < A_N / 4 / SNT; ++i) {
            float4 s4 = sptr[t + SNT * i];
            float s[4] = {s4.x, s4.y, s4.z, s4.w};
#pragma unroll
            for (int q = 0; q < 4; ++q) {
                if (s[q] > 0.3f) {
                    unsigned u = __float_as_uint(s[q]);
                    int bin = (int)(u >> 16) - (int)BIN_BASE;
                    bin = bin < 0 ? 0 : (bin > NBINS - 1 ? NBINS - 1 : bin);
                    if (bin >= bin_lo && bin < bin_hi) {
                        int slot = atomicAdd(&s_cnt, 1);
                        if (slot < CAP) {
                            unsigned a = (unsigned)(4 * (t + SNT * i) + q);
                            cand[slot] = ((unsigned long long)u << 32) | (unsigned)(~a);
                        }
                    }
                }
            }
        }
        __syncthreads();
        int C = s_cnt; if (C > CAP) C = CAP;

        if (C > 0) {
            if (wv == 0) {
                unsigned long long key[8];
#pragma unroll
                for (int r = 0; r < 8; ++r) {
                    int sidx = r * 64 + lane;
                    key[r] = (sidx < C) ? cand[sidx] : 0ull;
                }
#pragma unroll
                for (int k = 2; k <= CAP; k <<= 1) {
#pragma unroll
                    for (int j = k >> 1; j > 0; j >>= 1) {
                        if (j >= 64) {
                            int jr = j >> 6;
#pragma unroll
                            for (int r = 0; r < 8; ++r) {
                                int rp = r ^ jr;
                                if (rp > r) {
                                    int e = r * 64 + lane;
                                    bool up = ((e & k) == 0);
                                    unsigned long long va = key[r], vb = key[rp];
                                    bool sw = up ? (va < vb) : (va > vb);
                                    if (sw) { key[r] = vb; key[rp] = va; }
                                }
                            }
                        } else {
#pragma unroll
                            for (int r = 0; r < 8; ++r) {
                                int e = r * 64 + lane;
                                bool up    = ((e & k) == 0);
                                bool isLow = ((lane & j) == 0);
                                unsigned long long va = key[r];
                                unsigned long long vb = __shfl_xor(va, j, 64);
                                bool keepMax = (up == isLow);
                                key[r] = keepMax ? (va > vb ? va : vb)
                                                 : (va < vb ? va : vb);
                            }
                        }
                    }
                }
#pragma unroll
                for (int r = 0; r < 8; ++r) cand[r * 64 + lane] = key[r];
            }
            __syncthreads();

            for (int e = t; e < CAP; e += SNT)
                if (e < C) cbox[e] = bptr[(int)(~(unsigned)cand[e])];
            __syncthreads();

            if (wv == 0) {
                int ts = 0;
                unsigned long long k0 = cand[0];
                float4 cb = cbox[0];
                while (ts < C) {
                    unsigned long long nk = 0ull;
                    float4 nb = cb;
                    if (ts + 1 < C) { nk = cand[ts + 1]; nb = cbox[ts + 1]; }
                    float sc = __uint_as_float((unsigned)(k0 >> 32));
                    float ca = (cb.z - cb.x) * (cb.w - cb.y);
                    bool over = false;
                    if (lane < acc) {
                        float tlx = fmaxf(rx1, cb.x);
                        float tly = fmaxf(ry1, cb.y);
                        float brx = fminf(rx2, cb.z);
                        float bry = fminf(ry2, cb.w);
                        float iw  = fmaxf(brx - tlx, 0.0f);
                        float ih  = fmaxf(bry - tly, 0.0f);
                        float inter = iw * ih;
                        float iou = inter / (rar + ca - inter);
                        over = iou > 0.5f;
                    }
                    if (!__any(over)) {
                        if (lane == acc) { rx1 = cb.x; ry1 = cb.y; rx2 = cb.z; ry2 = cb.w; rar = ca; }
                        if (lane == 0) {
                            float* o = optr + (size_t)kout * 5;
                            o[0] = sc; o[1] = cb.x; o[2] = cb.y; o[3] = cb.z; o[4] = cb.w;
                        }
                        acc++; kout++;
                        if (acc == TOPK) break;
                    }
                    ++ts; k0 = nk; cb = nb;
                }
                if (lane == 0) { s_acc = acc; s_kout = kout; }
            }
            __syncthreads();
            if (s_acc >= TOPK) break;
        }
        bin_hi = bin_lo;
    }

    {
        const int ko = s_kout;
        float* o  = optr + (size_t)ko * 5;
        int   rem = (TOPK - ko) * 5;
        for (int i = t; i < rem; i += SNT) o[i] = 0.0f;
    }
}

// ---------------------------------------------------------------------------
// Tier-3 fallback: standalone one-wave NMS reading strided conf (r6-8 path).
// ---------------------------------------------------------------------------
__global__ __launch_bounds__(64, 4) void nms_fallback(const float* __restrict__ conf,
                                                      const float4* __restrict__ boxes,
                                                      float* __restrict__ out) {
    __shared__ int hist[NBINS];
    __shared__ unsigned long long cand[CAP];
    __shared__ float4 cbox[CAP];
    __shared__ int s_cnt;

    const int c    = blockIdx.x;
    const int b    = blockIdx.y;
    const int lane = threadIdx.x;

    const float4* bptr = boxes + (size_t)b * A_N;
    const float*  cptr = conf + (size_t)b * A_N * C_N + c;
    float* optr = out + (size_t)(b * C_N + c) * TOPK * 5;

    for (int i = lane; i < NBINS; i += 64) hist[i] = 0;
    __syncthreads();
    for (int i = 0; i < A_N / 256; ++i) {
        int a0 = 4 * (lane + 64 * i);
#pragma unroll
        for (int q = 0; q < 4; ++q) {
            float x = cptr[(size_t)(a0 + q) * C_N];
            float s = 1.0f / (1.0f + expf(-x));
            if (s > 0.3f) {
                unsigned u = __float_as_uint(s);
                int bin = (int)(u >> 16) - (int)BIN_BASE;
                bin = bin < 0 ? 0 : (bin > NBINS - 1 ? NBINS - 1 : bin);
                atomicAdd(&hist[bin], 1);
            }
        }
    }
    __syncthreads();

    float rx1 = 0.f, ry1 = 0.f, rx2 = 0.f, ry2 = 0.f, rar = 0.f;
    int acc = 0, kout = 0;
    int bin_hi = NBINS;
    for (;;) {
        int lo = bin_hi, tot = 0;
        while (lo > 0) {
            int cnt = hist[lo - 1];
            if (tot + cnt > CAP) { if (tot == 0) { lo--; } break; }
            tot += cnt; lo--;
        }
        const int bin_lo = lo;
        if (bin_lo == bin_hi) break;
        if (lane == 0) s_cnt = 0;
        __syncthreads();
        for (int i = 0; i < A_N / 256; ++i) {
            int a0 = 4 * (lane + 64 * i);
#pragma unroll
            for (int q = 0; q < 4; ++q) {
                float x = cptr[(size_t)(a0 + q) * C_N];
                float s = 1.0f / (1.0f + expf(-x));
                if (s > 0.3f) {
                    unsigned u = __float_as_uint(s);
                    int bin = (int)(u >> 16) - (int)BIN_BASE;
                    bin = bin < 0 ? 0 : (bin > NBINS - 1 ? NBINS - 1 : bin);
                    if (bin >= bin_lo && bin < bin_hi) {
                        int slot = atomicAdd(&s_cnt, 1);
                        if (slot < CAP)
                            cand[slot] = ((unsigned long long)u << 32) | (unsigned)(~(unsigned)(a0 + q));
                    }
                }
            }
        }
        __syncthreads();
        int C = s_cnt; if (C > CAP) C = CAP;
        if (C > 0)
            sort_gather_scan64(cand, cbox, C, lane, bptr, optr,
                               rx1, ry1, rx2, ry2, rar, acc, kout);
        if (acc == TOPK) break;
        bin_hi = bin_lo;
    }
    {
        float* o  = optr + (size_t)kout * 5;
        int   rem = (TOPK - kout) * 5;
        for (int i = lane; i < rem; i += 64) o[i] = 0.0f;
    }
}

extern "C" void kernel_launch(void* const* d_in, const int* in_sizes, int n_in,
                              void* d_out, int out_size, void* d_ws, size_t ws_size,
                              hipStream_t stream) {
    const float* loc     = (const float*)d_in[0];   // [B, A, 4]
    const float* conf    = (const float*)d_in[1];   // [B, A, C]
    const float* anchors = (const float*)d_in[2];   // [A, 4]
    float* out = (float*)d_out;                     // [B, C, TOPK, 5]

    const size_t boxes_bytes  = (size_t)B_N * A_N * sizeof(float4);          // 4 MB
    const size_t scores_bytes = (size_t)B_N * C_N * A_N * sizeof(float);     // 85 MB
    const size_t hist_bytes   = (size_t)BC_N * NBINS * sizeof(int);          // 1.2 MB
    const size_t fixed_bytes  = boxes_bytes + scores_bytes + hist_bytes;     // ~90.3 MB
    const size_t min_cand     = (size_t)BC_N * CAP * sizeof(unsigned long long); // 5.3 MB

    float4* boxes = (float4*)d_ws;

    decode_kernel<<<(B_N * A_N) / DNT, DNT, 0, stream>>>(
        (const float4*)loc, (const float4*)anchors, boxes);

    if (ws_size >= fixed_bytes + min_cand) {
        size_t avail = ws_size - fixed_bytes;
        int gcap = (int)(avail / ((size_t)BC_N * sizeof(unsigned long long)));
        if (gcap > GCAP_MAX) gcap = GCAP_MAX;

        char* p = (char*)d_ws + boxes_bytes;
        float* scoresT = (float*)p;                 p += scores_bytes;
        int* g_hist = (int*)p;                      p += hist_bytes;
        unsigned long long* g_cand = (unsigned long long*)p;

        sigT_kernel<<<dim3(A_N / TA, B_N), TNT, 0, stream>>>(conf, scoresT);
        select_kernel<<<dim3(BC_N), SNT, 0, stream>>>(scoresT, g_cand, g_hist, gcap);
        nms_banded_kernel<<<dim3(BC_N), 64, 0, stream>>>(scoresT, boxes, g_cand,
                                                         g_hist, out, gcap);
    } else if (ws_size >= boxes_bytes + scores_bytes) {
        float* scoresT = (float*)((char*)d_ws + boxes_bytes);
        sigT_kernel<<<dim3(A_N / TA, B_N), TNT, 0, stream>>>(conf, scoresT);
        select_nms_fused<<<dim3(BC_N), SNT, 0, stream>>>(scoresT, boxes, out);
    } else {
        nms_fallback<<<dim3(C_N, B_N), 64, 0, stream>>>(conf, boxes, out);
    }
}

// Round 8
// 216.061 us; speedup vs baseline: 1.7184x; 1.7184x over previous
//
#include <hip/hip_runtime.h>
#include <math.h>

// Problem constants (from reference setup_inputs): B=16, A=16384, C=81, TOP_K=64
constexpr int B_N  = 16;
constexpr int A_N  = 16384;
constexpr int C_N  = 81;
constexpr int TOPK = 64;
constexpr int DNT  = 256;            // decode kernel block size
constexpr int NBINS = 232;           // score-bit bins covering (0.3, 1.0)
constexpr int CAP   = 512;           // candidate band capacity (pow2, 8/lane)
constexpr unsigned BIN_BASE = 0x3E99u;   // __float_as_uint(0.3f) >> 16
constexpr int SNT = 256;             // fused select+nms block size

// Exact-compare: fl32(inter/den) > 0.5  <=>  (f64)inter > (f64)den*(0.5+2^-25)
// (24x25-bit mantissa product exact in f64; RN monotone.) Refcheck-proven in
// rounds 5-7. Selection bit-identical to the fp32 division form.
#define IOU_HALF_EXACT 0x1.000001p-1

// sigmoid+transpose tile: 64 anchors x 81 classes, linear LDS (round-1 v4,
// passed r1-r7; time identical to r0's v3).
constexpr int TA   = 64;
constexpr int TNT  = 256;
constexpr int TILE_ELEMS = TA * C_N;       // 5184
constexpr int TILE_F4    = TILE_ELEMS / 4; // 1296

// ---------------------------------------------------------------------------
// Kernel 1: SSD box decode (unchanged — bit-exact vs ref across all rounds).
// ---------------------------------------------------------------------------
__global__ __launch_bounds__(DNT) void decode_kernel(const float4* __restrict__ loc,
                                                     const float4* __restrict__ anch,
                                                     float4* __restrict__ boxes) {
    int i = blockIdx.x * DNT + threadIdx.x;
    int a = i & (A_N - 1);
    float4 l  = loc[i];
    float4 an = anch[a];
    float cx = an.x + (l.x * 0.1f) * an.z;
    float cy = an.y + (l.y * 0.1f) * an.w;
    float w  = an.z * expf(l.z * 0.2f);
    float h  = an.w * expf(l.w * 0.2f);
    float x1 = cx - w * 0.5f;
    float y1 = cy - h * 0.5f;
    boxes[i] = make_float4(x1, y1, x1 + w, y1 + h);
}

// ---------------------------------------------------------------------------
// Kernel 1b: fused sigmoid + transpose (round-1 v4, passed).
// ---------------------------------------------------------------------------
__global__ __launch_bounds__(TNT) void sigT_kernel(const float* __restrict__ conf,
                                                   float* __restrict__ scoresT) {
    __shared__ float4 tile4[TILE_F4];          // 20.7 KB, linear (mirrors global)
    float* tile = (float*)tile4;

    const int a0 = blockIdx.x * TA;
    const int b  = blockIdx.y;
    const int t  = threadIdx.x;

    const float4* src = (const float4*)(conf + ((size_t)b * A_N + a0) * C_N);
#pragma unroll
    for (int i = 0; i < (TILE_F4 + TNT - 1) / TNT; ++i) {   // 6 iters (last partial)
        int idx4 = i * TNT + t;
        if (idx4 < TILE_F4) {
            float4 x = src[idx4];                            // dwordx4, coalesced
            float4 v;
            v.x = 1.0f / (1.0f + expf(-x.x));
            v.y = 1.0f / (1.0f + expf(-x.y));
            v.z = 1.0f / (1.0f + expf(-x.z));
            v.w = 1.0f / (1.0f + expf(-x.w));
            tile4[idx4] = v;                                 // ds_write_b128, dense
        }
    }
    __syncthreads();
    float* dst = scoresT + (size_t)b * C_N * A_N + a0;
#pragma unroll
    for (int i = 0; i < (TILE_F4 + TNT - 1) / TNT; ++i) {
        int idx4 = i * TNT + t;
        if (idx4 < TILE_F4) {
            int cc  = idx4 >> 4;                   // 16 float4 per class row
            int al4 = idx4 & 15;
            int e   = al4 * 4 * C_N + cc;
            float4 v;
            v.x = tile[e];
            v.y = tile[e + C_N];
            v.z = tile[e + 2 * C_N];
            v.w = tile[e + 3 * C_N];
            ((float4*)(dst + (size_t)cc * A_N))[al4] = v;   // dwordx4 stores
        }
    }
}

// ---------------------------------------------------------------------------
// Exact IoU>0.5 test (accepted box A first — matches ref operand order).
// den = fl(fl(aA + aB) - inter), identical expression/order to all rounds.
// ---------------------------------------------------------------------------
__device__ __forceinline__ bool iou_gt_half(float Ax1, float Ay1, float Ax2,
                                            float Ay2, float aA,
                                            const float4& Bx, float aB) {
    float tlx = fmaxf(Ax1, Bx.x);
    float tly = fmaxf(Ay1, Bx.y);
    float brx = fminf(Ax2, Bx.z);
    float bry = fminf(Ay2, Bx.w);
    float iw  = fmaxf(brx - tlx, 0.0f);
    float ih  = fmaxf(bry - tly, 0.0f);
    float inter = iw * ih;
    float den = aA + aB - inter;
    return (double)inter > (double)den * IOU_HALF_EXACT;
}

// ---------------------------------------------------------------------------
// Kernel 2: FUSED select + NMS — round-0 kernel (measured best: 80.9 µs
// dispatch, 220.6 µs total) with two surgical scan changes:
//   (a) f64-exact IoU compare (bit-identical selection, proven r5-r7),
//   (b) 2-wide speculative scan step: candidates (ts, ts+1) tested against
//       the frozen accepted set + a uniform kill01 term — exactly the serial
//       recurrence unrolled by 2; TOPK break between the two accepts.
// Everything else (hist, band walk+clamp, keys, wave-0 bitonic sort, gather,
// zero-fill, launcher) is byte-identical to round 0.
// ---------------------------------------------------------------------------
__global__ __launch_bounds__(SNT, 4) void select_nms_kernel(
        const float* __restrict__ scoresT,
        const float4* __restrict__ boxes,
        float* __restrict__ out) {
    __shared__ int hist[NBINS];
    __shared__ unsigned long long cand[CAP];
    __shared__ float4 cbox[CAP];
    __shared__ int s_cnt, s_acc, s_kout;

    const int bc   = blockIdx.x;           // b*C_N + c
    const int b    = bc / C_N;
    const int t    = threadIdx.x;
    const int lane = t & 63;
    const int wv   = t >> 6;

    for (int i = t; i < NBINS; i += SNT) hist[i] = 0;
    if (t == 0) { s_acc = 0; s_kout = 0; }
    __syncthreads();

    const float4* sptr = (const float4*)(scoresT + (size_t)bc * A_N);
    const float4* bptr = boxes + (size_t)b * A_N;
    float* optr = out + (size_t)bc * TOPK * 5;

    // --- pass 1: histogram (256 threads, coalesced float4 reads) ---
    for (int i = 0; i < A_N / 4 / SNT; ++i) {      // 16 iterations
        float4 s4 = sptr[t + SNT * i];
        float s[4] = {s4.x, s4.y, s4.z, s4.w};
#pragma unroll
        for (int q = 0; q < 4; ++q) {
            if (s[q] > 0.3f) {
                unsigned u = __float_as_uint(s[q]);
                int bin = (int)(u >> 16) - (int)BIN_BASE;
                bin = bin < 0 ? 0 : (bin > NBINS - 1 ? NBINS - 1 : bin);
                atomicAdd(&hist[bin], 1);
            }
        }
    }
    __syncthreads();

    // Accepted boxes: one per lane of wave 0, in registers.
    float rx1 = 0.f, ry1 = 0.f, rx2 = 0.f, ry2 = 0.f, rar = 0.f;
    int acc = 0, kout = 0;                 // live on wave 0; mirrored via s_acc

    int bin_hi = NBINS;
    for (;;) {
        // --- band walk (redundant on all threads; wave-uniform LDS reads) ---
        int lo = bin_hi, tot = 0;
        while (lo > 0) {
            int cnt = hist[lo - 1];
            if (tot + cnt > CAP) {
                if (tot == 0) { lo--; }            // single bin > CAP: take it (clamped)
                break;
            }
            tot += cnt; lo--;
        }
        const int bin_lo = lo;
        if (bin_lo == bin_hi) break;               // all bins consumed -> exhausted
        if (t == 0) s_cnt = 0;
        __syncthreads();

        // --- pass 2: compact this band into LDS (256 threads, L2-warm reads) ---
        for (int i = 0; i < A_N / 4 / SNT; ++i) {
            float4 s4 = sptr[t + SNT * i];
            float s[4] = {s4.x, s4.y, s4.z, s4.w};
#pragma unroll
            for (int q = 0; q < 4; ++q) {
                if (s[q] > 0.3f) {
                    unsigned u = __float_as_uint(s[q]);
                    int bin = (int)(u >> 16) - (int)BIN_BASE;
                    bin = bin < 0 ? 0 : (bin > NBINS - 1 ? NBINS - 1 : bin);
                    if (bin >= bin_lo && bin < bin_hi) {
                        int slot = atomicAdd(&s_cnt, 1);
                        if (slot < CAP) {
                            unsigned a = (unsigned)(4 * (t + SNT * i) + q);
                            cand[slot] = ((unsigned long long)u << 32) | (unsigned)(~a);
                        }
                    }
                }
            }
        }
        __syncthreads();
        int C = s_cnt; if (C > CAP) C = CAP;       // uniform across block

        if (C > 0) {
            // --- wave-0 register bitonic sort (no barriers needed in-wave) ---
            if (wv == 0) {
                unsigned long long key[8];
#pragma unroll
                for (int r = 0; r < 8; ++r) {
                    int sidx = r * 64 + lane;
                    key[r] = (sidx < C) ? cand[sidx] : 0ull;   // pad: 0 < any real key
                }
#pragma unroll
                for (int k = 2; k <= CAP; k <<= 1) {
#pragma unroll
                    for (int j = k >> 1; j > 0; j >>= 1) {
                        if (j >= 64) {
                            int jr = j >> 6;               // 1,2,4: in-lane pairs
#pragma unroll
                            for (int r = 0; r < 8; ++r) {
                                int rp = r ^ jr;
                                if (rp > r) {
                                    int e = r * 64 + lane;
                                    bool up = ((e & k) == 0);
                                    unsigned long long va = key[r], vb = key[rp];
                                    bool sw = up ? (va < vb) : (va > vb);
                                    if (sw) { key[r] = vb; key[rp] = va; }
                                }
                            }
                        } else {                            // cross-lane via shfl
#pragma unroll
                            for (int r = 0; r < 8; ++r) {
                                int e = r * 64 + lane;
                                bool up    = ((e & k) == 0);
                                bool isLow = ((lane & j) == 0);
                                unsigned long long va = key[r];
                                unsigned long long vb = __shfl_xor(va, j, 64);
                                bool keepMax = (up == isLow);
                                key[r] = keepMax ? (va > vb ? va : vb)
                                                 : (va < vb ? va : vb);
                            }
                        }
                    }
                }
#pragma unroll
                for (int r = 0; r < 8; ++r) cand[r * 64 + lane] = key[r];
            }
            __syncthreads();

            // --- gather candidate boxes into LDS (256 threads, 2 each) ---
            for (int e = t; e < CAP; e += SNT)
                if (e < C) cbox[e] = bptr[(int)(~(unsigned)cand[e])];
            __syncthreads();

            // --- ordered greedy scan on wave 0 — 2-wide speculative step ---
            if (wv == 0) {
                int ts = 0;
                while (ts < C) {
                    unsigned long long k0 = cand[ts];      // uniform broadcasts
                    float4 cb = cbox[ts];
                    const bool have1 = (ts + 1 < C);
                    unsigned long long k1 = have1 ? cand[ts + 1] : 0ull;
                    float4 b1 = have1 ? cbox[ts + 1] : cb;
                    float ca0 = (cb.z - cb.x) * (cb.w - cb.y);
                    float ca1 = (b1.z - b1.x) * (b1.w - b1.y);

                    // both candidates vs the FROZEN accepted set (independent)
                    bool over0 = false, over1 = false;
                    if (lane < acc) {
                        over0 = iou_gt_half(rx1, ry1, rx2, ry2, rar, cb, ca0);
                        over1 = iou_gt_half(rx1, ry1, rx2, ry2, rar, b1, ca1);
                    }
                    // speculative: does cb (if accepted) kill b1? (wave-uniform)
                    bool kill01 = have1 &&
                        iou_gt_half(cb.x, cb.y, cb.z, cb.w, ca0, b1, ca1);

                    bool acc0 = !__any(over0);
                    bool any1 = __any(over1);

                    if (acc0) {
                        if (lane == acc) { rx1 = cb.x; ry1 = cb.y; rx2 = cb.z; ry2 = cb.w; rar = ca0; }
                        if (lane == 0) {
                            float* o = optr + (size_t)kout * 5;
                            o[0] = __uint_as_float((unsigned)(k0 >> 32));
                            o[1] = cb.x; o[2] = cb.y; o[3] = cb.z; o[4] = cb.w;
                        }
                        acc++; kout++;                      // wave-uniform
                        if (acc == TOPK) break;
                    }
                    if (have1 && !any1 && !(acc0 && kill01)) {
                        if (lane == acc) { rx1 = b1.x; ry1 = b1.y; rx2 = b1.z; ry2 = b1.w; rar = ca1; }
                        if (lane == 0) {
                            float* o = optr + (size_t)kout * 5;
                            o[0] = __uint_as_float((unsigned)(k1 >> 32));
                            o[1] = b1.x; o[2] = b1.y; o[3] = b1.z; o[4] = b1.w;
                        }
                        acc++; kout++;
                        if (acc == TOPK) break;
                    }
                    ts += 2;
                }
                if (lane == 0) { s_acc = acc; s_kout = kout; }
            }
            __syncthreads();
            if (s_acc >= TOPK) break;                      // uniform
            if (wv == 0) acc = s_acc;                      // keep (no-op; acc wave-0 local)
        }
        bin_hi = bin_lo;
    }

    // Zero-fill remaining rows (harness poisons d_out with 0xAA every launch).
    {
        const int ko = s_kout;                             // uniform (post-barrier)
        float* o  = optr + (size_t)ko * 5;
        int   rem = (TOPK - ko) * 5;
        for (int i = t; i < rem; i += SNT) o[i] = 0.0f;
    }
}

// ---------------------------------------------------------------------------
// Fallback pieces (round-0 verbatim): one-wave NMS reading strided conf,
// used only if d_ws is too small for scoresT.
// ---------------------------------------------------------------------------
__device__ __forceinline__ void sort_gather_scan64(
        unsigned long long* cand, float4* cbox, int C, int lane,
        const float4* __restrict__ bptr, float* __restrict__ optr,
        float& rx1, float& ry1, float& rx2, float& ry2, float& rar,
        int& acc, int& kout) {
    unsigned long long key[8];
#pragma unroll
    for (int r = 0; r < 8; ++r) {
        int sidx = r * 64 + lane;
        key[r] = (sidx < C) ? cand[sidx] : 0ull;
    }
#pragma unroll
    for (int k = 2; k <= CAP; k <<= 1) {
#pragma unroll
        for (int j = k >> 1; j > 0; j >>= 1) {
            if (j >= 64) {
                int jr = j >> 6;
#pragma unroll
                for (int r = 0; r < 8; ++r) {
                    int rp = r ^ jr;
                    if (rp > r) {
                        int e = r * 64 + lane;
                        bool up = ((e & k) == 0);
                        unsigned long long va = key[r], vb = key[rp];
                        bool sw = up ? (va < vb) : (va > vb);
                        if (sw) { key[r] = vb; key[rp] = va; }
                    }
                }
            } else {
#pragma unroll
                for (int r = 0; r < 8; ++r) {
                    int e = r * 64 + lane;
                    bool up    = ((e & k) == 0);
                    bool isLow = ((lane & j) == 0);
                    unsigned long long va = key[r];
                    unsigned long long vb = __shfl_xor(va, j, 64);
                    bool keepMax = (up == isLow);
                    key[r] = keepMax ? (va > vb ? va : vb) : (va < vb ? va : vb);
                }
            }
        }
    }
    __syncthreads();
#pragma unroll
    for (int r = 0; r < 8; ++r) cand[r * 64 + lane] = key[r];
    __syncthreads();
#pragma unroll
    for (int r = 0; r < 8; ++r) {
        int e = r * 64 + lane;
        if (e < C) cbox[e] = bptr[(int)(~(unsigned)cand[e])];
    }
    __syncthreads();

    int t = 0;
    unsigned long long k0 = cand[0];
    float4 cb = cbox[0];
    while (t < C) {
        unsigned long long nk = 0ull;
        float4 nb = cb;
        if (t + 1 < C) { nk = cand[t + 1]; nb = cbox[t + 1]; }
        float sc = __uint_as_float((unsigned)(k0 >> 32));
        float ca = (cb.z - cb.x) * (cb.w - cb.y);
        bool over = false;
        if (lane < acc) {
            float tlx = fmaxf(rx1, cb.x);
            float tly = fmaxf(ry1, cb.y);
            float brx = fminf(rx2, cb.z);
            float bry = fminf(ry2, cb.w);
            float iw  = fmaxf(brx - tlx, 0.0f);
            float ih  = fmaxf(bry - tly, 0.0f);
            float inter = iw * ih;
            float iou = inter / (rar + ca - inter);
            over = iou > 0.5f;
        }
        if (!__any(over)) {
            if (lane == acc) { rx1 = cb.x; ry1 = cb.y; rx2 = cb.z; ry2 = cb.w; rar = ca; }
            if (lane == 0) {
                float* o = optr + (size_t)kout * 5;
                o[0] = sc; o[1] = cb.x; o[2] = cb.y; o[3] = cb.z; o[4] = cb.w;
            }
            acc++; kout++;
            if (acc == TOPK) break;
        }
        ++t; k0 = nk; cb = nb;
    }
}

__global__ __launch_bounds__(64, 4) void nms_fallback(const float* __restrict__ conf,
                                                      const float4* __restrict__ boxes,
                                                      float* __restrict__ out) {
    __shared__ int hist[NBINS];
    __shared__ unsigned long long cand[CAP];
    __shared__ float4 cbox[CAP];
    __shared__ int s_cnt;

    const int c    = blockIdx.x;
    const int b    = blockIdx.y;
    const int lane = threadIdx.x;

    const float4* bptr = boxes + (size_t)b * A_N;
    const float*  cptr = conf + (size_t)b * A_N * C_N + c;
    float* optr = out + (size_t)(b * C_N + c) * TOPK * 5;

    for (int i = lane; i < NBINS; i += 64) hist[i] = 0;
    __syncthreads();
    for (int i = 0; i < A_N / 256; ++i) {
        int a0 = 4 * (lane + 64 * i);
#pragma unroll
        for (int q = 0; q < 4; ++q) {
            float x = cptr[(size_t)(a0 + q) * C_N];
            float s = 1.0f / (1.0f + expf(-x));
            if (s > 0.3f) {
                unsigned u = __float_as_uint(s);
                int bin = (int)(u >> 16) - (int)BIN_BASE;
                bin = bin < 0 ? 0 : (bin > NBINS - 1 ? NBINS - 1 : bin);
                atomicAdd(&hist[bin], 1);
            }
        }
    }
    __syncthreads();

    float rx1 = 0.f, ry1 = 0.f, rx2 = 0.f, ry2 = 0.f, rar = 0.f;
    int acc = 0, kout = 0;
    int bin_hi = NBINS;
    for (;;) {
        int lo = bin_hi, tot = 0;
        while (lo > 0) {
            int cnt = hist[lo - 1];
            if (tot + cnt > CAP) { if (tot == 0) { lo--; } break; }
            tot += cnt; lo--;
        }
        const int bin_lo = lo;
        if (bin_lo == bin_hi) break;
        if (lane == 0) s_cnt = 0;
        __syncthreads();
        for (int i = 0; i < A_N / 256; ++i) {
            int a0 = 4 * (lane + 64 * i);
#pragma unroll
            for (int q = 0; q < 4; ++q) {
                float x = cptr[(size_t)(a0 + q) * C_N];
                float s = 1.0f / (1.0f + expf(-x));
                if (s > 0.3f) {
                    unsigned u = __float_as_uint(s);
                    int bin = (int)(u >> 16) - (int)BIN_BASE;
                    bin = bin < 0 ? 0 : (bin > NBINS - 1 ? NBINS - 1 : bin);
                    if (bin >= bin_lo && bin < bin_hi) {
                        int slot = atomicAdd(&s_cnt, 1);
                        if (slot < CAP)
                            cand[slot] = ((unsigned long long)u << 32) | (unsigned)(~(unsigned)(a0 + q));
                    }
                }
            }
        }
        __syncthreads();
        int C = s_cnt; if (C > CAP) C = CAP;
        if (C > 0)
            sort_gather_scan64(cand, cbox, C, lane, bptr, optr,
                               rx1, ry1, rx2, ry2, rar, acc, kout);
        if (acc == TOPK) break;
        bin_hi = bin_lo;
    }
    {
        float* o  = optr + (size_t)kout * 5;
        int   rem = (TOPK - kout) * 5;
        for (int i = lane; i < rem; i += 64) o[i] = 0.0f;
    }
}

extern "C" void kernel_launch(void* const* d_in, const int* in_sizes, int n_in,
                              void* d_out, int out_size, void* d_ws, size_t ws_size,
                              hipStream_t stream) {
    const float* loc     = (const float*)d_in[0];   // [B, A, 4]
    const float* conf    = (const float*)d_in[1];   // [B, A, C]
    const float* anchors = (const float*)d_in[2];   // [A, 4]
    float* out = (float*)d_out;                     // [B, C, TOPK, 5]

    const size_t boxes_bytes  = (size_t)B_N * A_N * sizeof(float4);          // 4 MB
    const size_t scores_bytes = (size_t)B_N * C_N * A_N * sizeof(float);     // 85 MB

    float4* boxes = (float4*)d_ws;

    decode_kernel<<<(B_N * A_N) / DNT, DNT, 0, stream>>>(
        (const float4*)loc, (const float4*)anchors, boxes);

    if (ws_size >= boxes_bytes + scores_bytes) {
        float* scoresT = (float*)((char*)d_ws + boxes_bytes);
        sigT_kernel<<<dim3(A_N / TA, B_N), TNT, 0, stream>>>(conf, scoresT);
        select_nms_kernel<<<dim3(B_N * C_N), SNT, 0, stream>>>(scoresT, boxes, out);
    } else {
        // fallback: strided conf reads, in-wave histogram (proven semantics)
        nms_fallback<<<dim3(C_N, B_N), 64, 0, stream>>>(conf, boxes, out);
    }
}